// Round 8
// baseline (996.667 us; speedup 1.0000x reference)
//
#include <hip/hip_runtime.h>
#include <hip/hip_bf16.h>

// ---------------------------------------------------------------------------
// RewaHierarchicalAttention: x->QKV proj (bf16 MFMA GEMM), 3-level bucket-sorted
// chunked attention (flash-style, 16x16x32 bf16 MFMA), combine, output proj.
// B=4, N=4096, E=1024, H=16, DH=64. Chunks: 256/64/16.
// ---------------------------------------------------------------------------

typedef unsigned short u16;
typedef u16  u16x8 __attribute__((ext_vector_type(8)));
typedef u16  u16x4v __attribute__((ext_vector_type(4)));
typedef float f32x4 __attribute__((ext_vector_type(4)));
typedef __bf16 bf16x8 __attribute__((ext_vector_type(8)));

__device__ __forceinline__ u16 f2bf(float f) {
    unsigned u = __builtin_bit_cast(unsigned, f);
    u += 0x7fffu + ((u >> 16) & 1u);          // round-to-nearest-even
    return (u16)(u >> 16);
}
__device__ __forceinline__ float bf2f(u16 b) {
    unsigned u = ((unsigned)b) << 16;
    return __builtin_bit_cast(float, u);
}
__device__ __forceinline__ f32x4 mfma16(u16x8 a, u16x8 b, f32x4 c) {
    return __builtin_amdgcn_mfma_f32_16x16x32_bf16(
        __builtin_bit_cast(bf16x8, a), __builtin_bit_cast(bf16x8, b), c, 0, 0, 0);
}

// ---------------------------------------------------------------------------
// fp32 -> bf16 convert (vectorized, grid-stride)
// ---------------------------------------------------------------------------
__global__ void cvt_kernel(const float* __restrict__ in, u16* __restrict__ outp, int n) {
    int i = (blockIdx.x * 256 + threadIdx.x) * 4;
    const int stride = gridDim.x * 256 * 4;
    for (; i < n; i += stride) {
        const float4 f = *(const float4*)(in + i);
        u16x4v o;
        o[0] = f2bf(f.x); o[1] = f2bf(f.y); o[2] = f2bf(f.z); o[3] = f2bf(f.w);
        *(u16x4v*)(outp + i) = o;
    }
}

// ---------------------------------------------------------------------------
// Stable counting argsort per (level, batch). Values < 256. Matches
// jnp.argsort (ascending, stable). grid = (4 batches, 3 levels), block 256.
// ---------------------------------------------------------------------------
__global__ void sort_kernel(const int* __restrict__ wb0, const int* __restrict__ wb1,
                            const int* __restrict__ wb2, int* __restrict__ sidx) {
    const int lvl = blockIdx.y;
    const int b = blockIdx.x;
    const int* wb = (lvl == 0) ? wb0 : (lvl == 1) ? wb1 : wb2;
    const int nb = (lvl == 0) ? 16 : (lvl == 1) ? 64 : 256;
    int* outp = sidx + (lvl * 4 + b) * 4096;
    __shared__ int lb[4096];
    __shared__ int cnt[257];
    const int t = threadIdx.x;
    for (int i = t; i < 4096; i += 256) lb[i] = wb[b * 4096 + i];
    __syncthreads();
    if (t < nb) {
        int c = 0;
        for (int i = 0; i < 4096; i++) c += (lb[i] == t);
        cnt[t + 1] = c;
    }
    if (t == 0) cnt[0] = 0;
    __syncthreads();
    if (t == 0) { for (int v = 0; v < nb; v++) cnt[v + 1] += cnt[v]; }
    __syncthreads();
    if (t < nb) {
        int pos = cnt[t];
        for (int i = 0; i < 4096; i++) {
            if (lb[i] == t) outp[pos++] = i;  // stable: original order within bucket
        }
    }
}

// ---------------------------------------------------------------------------
// GEMM: out[M,N] = A[M,K](bf16) * Bm[N,K]^T(bf16) + bias[N], 128x128 tile,
// BK=32, 4 waves, reg-staged LDS. XOR swizzle uses ONLY (row&3): the in-row
// offset field is 2 bits (4 x 16B pieces per 32-elem row); using (row&7)
// would set bit 5 and escape the row slot (row 7 would collide with row 8).
// OUTF32=0 -> bf16 out, OUTF32=1 -> fp32 out.
// ---------------------------------------------------------------------------
template <int OUTF32>
__global__ __launch_bounds__(256) void gemm_bt(const u16* __restrict__ A,
                                               const u16* __restrict__ Bm,
                                               const float* __restrict__ bias,
                                               void* __restrict__ outp,
                                               int M, int N, int K) {
    __shared__ __align__(16) u16 Al[128 * 32];
    __shared__ __align__(16) u16 Bl[128 * 32];
    const int tid = threadIdx.x;
    const int lane = tid & 63, w = tid >> 6;
    const int m0 = blockIdx.x * 128, n0 = blockIdx.y * 128;
    const int wr = w >> 1, wc = w & 1;
    const int fr = lane & 15, fg = lane >> 4;

    // staging map: thread -> (row, 16B piece); rows r and r+64
    const int r0s = tid >> 2;
    const int kp = (tid & 3) * 8;  // ushort offset in [0,32)
    const u16* Ag = A + (size_t)(m0 + r0s) * K + kp;
    const u16* Bg = Bm + (size_t)(n0 + r0s) * K + kp;

    u16x8 a0 = *(const u16x8*)(Ag);
    u16x8 a1 = *(const u16x8*)(Ag + (size_t)64 * K);
    u16x8 b0 = *(const u16x8*)(Bg);
    u16x8 b1 = *(const u16x8*)(Bg + (size_t)64 * K);

    f32x4 acc[4][4] = {};

    const int row0 = r0s, row1 = r0s + 64;
    const int wA0 = row0 * 32 + (kp ^ ((row0 & 3) << 3));
    const int wA1 = row1 * 32 + (kp ^ ((row1 & 3) << 3));

    for (int k0 = 0; k0 < K; k0 += 32) {
        __syncthreads();
        *(u16x8*)&Al[wA0] = a0;
        *(u16x8*)&Al[wA1] = a1;
        *(u16x8*)&Bl[wA0] = b0;
        *(u16x8*)&Bl[wA1] = b1;
        __syncthreads();
        if (k0 + 32 < K) {
            a0 = *(const u16x8*)(Ag + k0 + 32);
            a1 = *(const u16x8*)(Ag + (size_t)64 * K + k0 + 32);
            b0 = *(const u16x8*)(Bg + k0 + 32);
            b1 = *(const u16x8*)(Bg + (size_t)64 * K + k0 + 32);
        }
        u16x8 af[4], bf[4];
#pragma unroll
        for (int i = 0; i < 4; i++) {
            const int ar = wr * 64 + i * 16 + fr;
            af[i] = *(const u16x8*)&Al[ar * 32 + ((fg * 8) ^ ((ar & 3) << 3))];
            const int br = wc * 64 + i * 16 + fr;
            bf[i] = *(const u16x8*)&Bl[br * 32 + ((fg * 8) ^ ((br & 3) << 3))];
        }
#pragma unroll
        for (int i = 0; i < 4; i++)
#pragma unroll
            for (int j = 0; j < 4; j++)
                acc[i][j] = mfma16(af[i], bf[j], acc[i][j]);
    }

#pragma unroll
    for (int i = 0; i < 4; i++) {
#pragma unroll
        for (int j = 0; j < 4; j++) {
            const int col = n0 + wc * 64 + j * 16 + fr;
            const float bs = bias[col];
#pragma unroll
            for (int r = 0; r < 4; r++) {
                const int row = m0 + wr * 64 + i * 16 + fg * 4 + r;
                const float v = acc[i][j][r] + bs;
                if (OUTF32)
                    ((float*)outp)[(size_t)row * N + col] = v;
                else
                    ((u16*)outp)[(size_t)row * N + col] = f2bf(v);
            }
        }
    }
}

// ---------------------------------------------------------------------------
// Chunked attention, all 3 levels (blockIdx.z). Block = 256 thr = 4 waves,
// 64 sorted rows per block (16/wave). Flash over 128-key LDS supertiles.
// K staged row-major XOR-swizzled; V staged transposed (d-major) XOR-swizzled.
// ---------------------------------------------------------------------------
__global__ __launch_bounds__(256) void attn_kernel(const u16* __restrict__ qb,
                                                   const u16* __restrict__ kb,
                                                   const u16* __restrict__ vb,
                                                   const int* __restrict__ sidx,
                                                   u16* __restrict__ att0) {
    __shared__ __align__(16) u16 Ksw[128 * 64];
    __shared__ __align__(16) u16 Vt[64 * 128];
    __shared__ __align__(16) u16 Pl[4][16 * 40];

    const int tid = threadIdx.x;
    const int lane = tid & 63;
    const int w = tid >> 6;
    const int fr = lane & 15, fg = lane >> 4;

    const int lvl = blockIdx.z;
    const int C = (lvl == 0) ? 256 : ((lvl == 1) ? 64 : 16);
    const int bh = blockIdx.y;
    const int b = bh >> 4, h = bh & 15;
    const int r0 = blockIdx.x * 64;
    const int* sb = sidx + (lvl * 4 + b) * 4096;
    u16* aout = att0 + (size_t)lvl * 16777216u;

    const int rowbase = r0 + w * 16;
    const int cw = rowbase / C;
    const int kstart = (cw > 0) ? (cw - 1) * C : 0;
    const int kend = (cw + 1) * C;
    const int c0 = r0 / C;
    const int W0 = (c0 > 0) ? (c0 - 1) * C : 0;
    const int cl = (r0 + 63) / C;
    const int W1 = (cl + 1) * C;
    const int nwin = W1 - W0;

    // Q A-fragments (rows rowbase + fr), d halves [0,32) / [32,64)
    const int qorig = sb[rowbase + fr];
    const u16* qp = qb + ((size_t)(b * 4096 + qorig) << 10) + h * 64;
    const u16x8 qf0 = *(const u16x8*)(qp + fg * 8);
    const u16x8 qf1 = *(const u16x8*)(qp + 32 + fg * 8);

    float m[4], l[4];
    f32x4 o[4] = {};
#pragma unroll
    for (int r = 0; r < 4; r++) { m[r] = -1e30f; l[r] = 0.f; }

    for (int st = 0; st < nwin; st += 128) {
        const int nstage = min(128, nwin - st);
        __syncthreads();
        {
            const int jj = tid >> 3;
            const int piece = tid & 7;
#pragma unroll
            for (int j0 = 0; j0 < 128; j0 += 32) {
                const int j = j0 + jj;
                u16x8 kv = {0, 0, 0, 0, 0, 0, 0, 0};
                u16x8 vv = {0, 0, 0, 0, 0, 0, 0, 0};
                if (j < nstage) {
                    const int orig = sb[W0 + st + j];
                    const size_t gofs = ((size_t)(b * 4096 + orig) << 10) + h * 64 + piece * 8;
                    kv = *(const u16x8*)(kb + gofs);
                    vv = *(const u16x8*)(vb + gofs);
                }
                *(u16x8*)&Ksw[j * 64 + ((piece * 8) ^ ((j & 7) << 3))] = kv;
#pragma unroll
                for (int u = 0; u < 8; u++) {
                    const int d = piece * 8 + u;
                    Vt[d * 128 + (j ^ ((d & 7) << 3))] = vv[u];
                }
            }
        }
        __syncthreads();

        const int base = W0 + st;
        const int lo = max(kstart, base) - base;
        const int hi = min(kend, base + nstage) - base;
        for (int kt = lo; kt < hi; kt += 32) {
            const int kr0 = kt + fr;
            const int kr1 = kr0 + 16;
            const u16x8 kf00 = *(const u16x8*)&Ksw[kr0 * 64 + ((fg * 8) ^ ((kr0 & 7) << 3))];
            const u16x8 kf01 = *(const u16x8*)&Ksw[kr0 * 64 + ((32 + fg * 8) ^ ((kr0 & 7) << 3))];
            const u16x8 kf10 = *(const u16x8*)&Ksw[kr1 * 64 + ((fg * 8) ^ ((kr1 & 7) << 3))];
            const u16x8 kf11 = *(const u16x8*)&Ksw[kr1 * 64 + ((32 + fg * 8) ^ ((kr1 & 7) << 3))];
            f32x4 s0 = {0.f, 0.f, 0.f, 0.f}, s1 = {0.f, 0.f, 0.f, 0.f};
            s0 = mfma16(qf0, kf00, s0);
            s0 = mfma16(qf1, kf01, s0);
            s1 = mfma16(qf0, kf10, s1);
            s1 = mfma16(qf1, kf11, s1);
            const bool f1ok = (kt + 16) < hi;
            f32x4 mx;
#pragma unroll
            for (int r = 0; r < 4; r++) {
                s0[r] *= 0.125f;
                s1[r] = f1ok ? s1[r] * 0.125f : -1e30f;
                mx[r] = fmaxf(s0[r], s1[r]);
            }
#pragma unroll
            for (int sh = 1; sh < 16; sh <<= 1)
#pragma unroll
                for (int r = 0; r < 4; r++) mx[r] = fmaxf(mx[r], __shfl_xor(mx[r], sh));
            float alpha[4];
            f32x4 p0, p1, ps;
#pragma unroll
            for (int r = 0; r < 4; r++) {
                const float mn = fmaxf(m[r], mx[r]);
                alpha[r] = exp2f((m[r] - mn) * 1.44269504f);
                m[r] = mn;
                p0[r] = exp2f((s0[r] - mn) * 1.44269504f);
                p1[r] = exp2f((s1[r] - mn) * 1.44269504f);
                ps[r] = p0[r] + p1[r];
            }
#pragma unroll
            for (int sh = 1; sh < 16; sh <<= 1)
#pragma unroll
                for (int r = 0; r < 4; r++) ps[r] += __shfl_xor(ps[r], sh);
            u16* pw = &Pl[w][0];
#pragma unroll
            for (int r = 0; r < 4; r++) {
                l[r] = l[r] * alpha[r] + ps[r];
                const int prow = fg * 4 + r;
                pw[prow * 40 + fr] = f2bf(p0[r]);
                pw[prow * 40 + 16 + fr] = f2bf(p1[r]);
#pragma unroll
                for (int dt = 0; dt < 4; dt++) o[dt][r] *= alpha[r];
            }
            const u16x8 pa = *(const u16x8*)&pw[fr * 40 + fg * 8];
#pragma unroll
            for (int dt = 0; dt < 4; dt++) {
                const int d = dt * 16 + fr;
                const u16x8 vf = *(const u16x8*)&Vt[d * 128 + ((kt + fg * 8) ^ ((d & 7) << 3))];
                o[dt] = mfma16(pa, vf, o[dt]);
            }
        }
    }

#pragma unroll
    for (int r = 0; r < 4; r++) {
        const float inv = 1.0f / l[r];
        const int orow = sb[rowbase + fg * 4 + r];
        u16* op = aout + ((size_t)(b * 4096 + orow) << 10) + h * 64 + fr;
#pragma unroll
        for (int dt = 0; dt < 4; dt++) op[dt * 16] = f2bf(o[dt][r] * inv);
    }
}

// ---------------------------------------------------------------------------
// combine: (a0+a1+a2)/3 -> bf16
// ---------------------------------------------------------------------------
__global__ void combine_kernel(const u16* __restrict__ a0, const u16* __restrict__ a1,
                               const u16* __restrict__ a2, u16* __restrict__ outp, int n) {
    int i = (blockIdx.x * 256 + threadIdx.x) * 8;
    const int stride = gridDim.x * 256 * 8;
    for (; i < n; i += stride) {
        const u16x8 v0 = *(const u16x8*)(a0 + i);
        const u16x8 v1 = *(const u16x8*)(a1 + i);
        const u16x8 v2 = *(const u16x8*)(a2 + i);
        u16x8 ov;
#pragma unroll
        for (int e = 0; e < 8; e++) {
            const float s = (bf2f(v0[e]) + bf2f(v1[e]) + bf2f(v2[e])) * (1.0f / 3.0f);
            ov[e] = f2bf(s);
        }
        *(u16x8*)(outp + i) = ov;
    }
}

// ---------------------------------------------------------------------------
extern "C" void kernel_launch(void* const* d_in, const int* in_sizes, int n_in,
                              void* d_out, int out_size, void* d_ws, size_t ws_size,
                              hipStream_t stream) {
    (void)in_sizes; (void)n_in; (void)out_size; (void)ws_size;
    const float* x  = (const float*)d_in[0];
    const float* Wq = (const float*)d_in[1];
    const float* bq = (const float*)d_in[2];
    const float* Wk = (const float*)d_in[3];
    const float* bk = (const float*)d_in[4];
    const float* Wv = (const float*)d_in[5];
    const float* bv = (const float*)d_in[6];
    const float* Wo = (const float*)d_in[7];
    const float* bo = (const float*)d_in[8];
    const int* wbc = (const int*)d_in[9];
    const int* wbm = (const int*)d_in[10];
    const int* wbf = (const int*)d_in[11];

    const size_t ELT_X = 16777216;  // 16384*1024
    const size_t ELT_W = 1048576;   // 1024*1024

    char* p = (char*)d_ws;
    u16* xb   = (u16*)p; p += ELT_X * 2;   // later reused as 'comb'
    u16* wqb  = (u16*)p; p += ELT_W * 2;
    u16* wkb  = (u16*)p; p += ELT_W * 2;
    u16* wvb  = (u16*)p; p += ELT_W * 2;
    u16* wob  = (u16*)p; p += ELT_W * 2;
    u16* qbuf = (u16*)p; p += ELT_X * 2;
    u16* kbuf = (u16*)p; p += ELT_X * 2;
    u16* vbuf = (u16*)p; p += ELT_X * 2;
    u16* att0 = (u16*)p; p += 3 * ELT_X * 2;
    int* sidx = (int*)p; p += 3 * 4 * 4096 * 4;

    // 1) converts
    cvt_kernel<<<4096, 256, 0, stream>>>(x, xb, (int)ELT_X);
    cvt_kernel<<<512, 256, 0, stream>>>(Wq, wqb, (int)ELT_W);
    cvt_kernel<<<512, 256, 0, stream>>>(Wk, wkb, (int)ELT_W);
    cvt_kernel<<<512, 256, 0, stream>>>(Wv, wvb, (int)ELT_W);
    cvt_kernel<<<512, 256, 0, stream>>>(Wo, wob, (int)ELT_W);

    // 2) stable bucket argsort (3 levels x 4 batches)
    sort_kernel<<<dim3(4, 3), 256, 0, stream>>>(wbc, wbm, wbf, sidx);

    // 3) QKV projections
    gemm_bt<0><<<dim3(128, 8), 256, 0, stream>>>(xb, wqb, bq, qbuf, 16384, 1024, 1024);
    gemm_bt<0><<<dim3(128, 8), 256, 0, stream>>>(xb, wkb, bk, kbuf, 16384, 1024, 1024);
    gemm_bt<0><<<dim3(128, 8), 256, 0, stream>>>(xb, wvb, bv, vbuf, 16384, 1024, 1024);

    // 4) chunked attention, all levels in one launch
    attn_kernel<<<dim3(64, 64, 3), 256, 0, stream>>>(qbuf, kbuf, vbuf, sidx, att0);

    // 5) combine levels -> bf16 (reuse xb)
    combine_kernel<<<4096, 256, 0, stream>>>(att0, att0 + ELT_X, att0 + 2 * ELT_X, xb,
                                             (int)ELT_X);

    // 6) output projection (fp32 out + bias)
    gemm_bt<1><<<dim3(128, 8), 256, 0, stream>>>(xb, wob, bo, d_out, 16384, 1024, 1024);
}

// Round 12
// 681.366 us; speedup vs baseline: 1.4627x; 1.4627x over previous
//
#include <hip/hip_runtime.h>
#include <hip/hip_bf16.h>

// ---------------------------------------------------------------------------
// RewaHierarchicalAttention: x->QKV proj (bf16 MFMA GEMM), 3-level bucket-sorted
// chunked attention (flash-style, 16x16x32 bf16 MFMA), combine, output proj.
// B=4, N=4096, E=1024, H=16, DH=64. Chunks: 256/64/16.
// ---------------------------------------------------------------------------

typedef unsigned short u16;
typedef unsigned char u8;
typedef u16  u16x8 __attribute__((ext_vector_type(8)));
typedef u16  u16x4v __attribute__((ext_vector_type(4)));
typedef float f32x4 __attribute__((ext_vector_type(4)));
typedef __bf16 bf16x8 __attribute__((ext_vector_type(8)));

__device__ __forceinline__ u16 f2bf(float f) {
    unsigned u = __builtin_bit_cast(unsigned, f);
    u += 0x7fffu + ((u >> 16) & 1u);          // round-to-nearest-even
    return (u16)(u >> 16);
}
__device__ __forceinline__ float bf2f(u16 b) {
    unsigned u = ((unsigned)b) << 16;
    return __builtin_bit_cast(float, u);
}
__device__ __forceinline__ f32x4 mfma16(u16x8 a, u16x8 b, f32x4 c) {
    return __builtin_amdgcn_mfma_f32_16x16x32_bf16(
        __builtin_bit_cast(bf16x8, a), __builtin_bit_cast(bf16x8, b), c, 0, 0, 0);
}

// ---------------------------------------------------------------------------
// fp32 -> bf16 convert (vectorized, grid-stride)
// ---------------------------------------------------------------------------
__global__ void cvt_kernel(const float* __restrict__ in, u16* __restrict__ outp, int n) {
    int i = (blockIdx.x * 256 + threadIdx.x) * 4;
    const int stride = gridDim.x * 256 * 4;
    for (; i < n; i += stride) {
        const float4 f = *(const float4*)(in + i);
        u16x4v o;
        o[0] = f2bf(f.x); o[1] = f2bf(f.y); o[2] = f2bf(f.z); o[3] = f2bf(f.w);
        *(u16x4v*)(outp + i) = o;
    }
}

// ---------------------------------------------------------------------------
// Parallel stable counting argsort per (level, batch). Values < 256. Matches
// jnp.argsort (ascending, stable). grid = (4 batches, 3 levels), block 256.
// Chunked: thread t owns chunk t (32 elements). Per-chunk histogram ->
// column totals -> exclusive base -> column scan (counts -> start offsets,
// u16 ok since N=4096) -> stable scatter (each (chunk,bucket) cell owned by
// one thread, walked in element order => stable). Row stride 258 u16 breaks
// the 512B-row bank-0 pattern. LDS ~70 KB (< 160 KB gfx950 max).
// ---------------------------------------------------------------------------
__global__ __launch_bounds__(256) void sort_kernel(const int* __restrict__ wb0, const int* __restrict__ wb1,
                            const int* __restrict__ wb2, int* __restrict__ sidx) {
    const int lvl = blockIdx.y;
    const int b = blockIdx.x;
    const int* wb = (lvl == 0) ? wb0 : (lvl == 1) ? wb1 : wb2;
    const int nb = (lvl == 0) ? 16 : (lvl == 1) ? 64 : 256;
    int* outp = sidx + (lvl * 4 + b) * 4096;
    __shared__ u8 lb[4096];
    __shared__ int base[257];
    __shared__ __align__(16) u16 ch[128][258];   // [chunk][bucket], padded stride
    const int t = threadIdx.x;

    // coalesced load (bucket values < 256 fit u8)
    for (int i = t; i < 4096; i += 256) lb[i] = (u8)wb[b * 4096 + i];
    // zero ch (flat: 128*258 u16 = 33024 u16 = 4128 uint4)
    {
        uint4 z = {0u, 0u, 0u, 0u};
        uint4* zp = (uint4*)&ch[0][0];
        for (int i = t; i < 4128; i += 256) zp[i] = z;
    }
    __syncthreads();

    // per-chunk histogram: thread t<128 owns elements [t*32, t*32+32)
    if (t < 128) {
        const int s = t * 32;
        for (int e = 0; e < 32; e++) ch[t][lb[s + e]]++;
    }
    __syncthreads();

    // bucket totals: thread v<nb sums column v over chunks
    if (t < nb) {
        int c = 0;
        for (int k = 0; k < 128; k++) c += ch[k][t];
        base[t + 1] = c;
    }
    if (t == 0) base[0] = 0;
    __syncthreads();
    if (t == 0) { for (int v = 0; v < nb; v++) base[v + 1] += base[v]; }
    __syncthreads();

    // column-wise exclusive scan: counts -> starting global offsets
    if (t < nb) {
        int run = base[t];
        for (int k = 0; k < 128; k++) {
            const int c = ch[k][t];
            ch[k][t] = (u16)run;
            run += c;
        }
    }
    __syncthreads();

    // stable scatter: walk own chunk in element order
    if (t < 128) {
        const int s = t * 32;
        for (int e = 0; e < 32; e++) {
            const int v = lb[s + e];
            const int pos = ch[t][v]++;
            outp[pos] = s + e;
        }
    }
}

// ---------------------------------------------------------------------------
// GEMM: out[M,N] = A[M,K](bf16) * Bm[N,K]^T(bf16) + bias[N], 128x128 tile,
// BK=32, 4 waves, reg-staged LDS. XOR swizzle uses ONLY (row&3): the in-row
// offset field is 2 bits (4 x 16B pieces per 32-elem row); using (row&7)
// would set bit 5 and escape the row slot (row 7 would collide with row 8).
// OUTF32=0 -> bf16 out, OUTF32=1 -> fp32 out.
// ---------------------------------------------------------------------------
template <int OUTF32>
__global__ __launch_bounds__(256) void gemm_bt(const u16* __restrict__ A,
                                               const u16* __restrict__ Bm,
                                               const float* __restrict__ bias,
                                               void* __restrict__ outp,
                                               int M, int N, int K) {
    __shared__ __align__(16) u16 Al[128 * 32];
    __shared__ __align__(16) u16 Bl[128 * 32];
    const int tid = threadIdx.x;
    const int lane = tid & 63, w = tid >> 6;
    const int m0 = blockIdx.x * 128, n0 = blockIdx.y * 128;
    const int wr = w >> 1, wc = w & 1;
    const int fr = lane & 15, fg = lane >> 4;

    // staging map: thread -> (row, 16B piece); rows r and r+64
    const int r0s = tid >> 2;
    const int kp = (tid & 3) * 8;  // ushort offset in [0,32)
    const u16* Ag = A + (size_t)(m0 + r0s) * K + kp;
    const u16* Bg = Bm + (size_t)(n0 + r0s) * K + kp;

    u16x8 a0 = *(const u16x8*)(Ag);
    u16x8 a1 = *(const u16x8*)(Ag + (size_t)64 * K);
    u16x8 b0 = *(const u16x8*)(Bg);
    u16x8 b1 = *(const u16x8*)(Bg + (size_t)64 * K);

    f32x4 acc[4][4] = {};

    const int row0 = r0s, row1 = r0s + 64;
    const int wA0 = row0 * 32 + (kp ^ ((row0 & 3) << 3));
    const int wA1 = row1 * 32 + (kp ^ ((row1 & 3) << 3));

    for (int k0 = 0; k0 < K; k0 += 32) {
        __syncthreads();
        *(u16x8*)&Al[wA0] = a0;
        *(u16x8*)&Al[wA1] = a1;
        *(u16x8*)&Bl[wA0] = b0;
        *(u16x8*)&Bl[wA1] = b1;
        __syncthreads();
        if (k0 + 32 < K) {
            a0 = *(const u16x8*)(Ag + k0 + 32);
            a1 = *(const u16x8*)(Ag + (size_t)64 * K + k0 + 32);
            b0 = *(const u16x8*)(Bg + k0 + 32);
            b1 = *(const u16x8*)(Bg + (size_t)64 * K + k0 + 32);
        }
        u16x8 af[4], bf[4];
#pragma unroll
        for (int i = 0; i < 4; i++) {
            const int ar = wr * 64 + i * 16 + fr;
            af[i] = *(const u16x8*)&Al[ar * 32 + ((fg * 8) ^ ((ar & 3) << 3))];
            const int br = wc * 64 + i * 16 + fr;
            bf[i] = *(const u16x8*)&Bl[br * 32 + ((fg * 8) ^ ((br & 3) << 3))];
        }
#pragma unroll
        for (int i = 0; i < 4; i++)
#pragma unroll
            for (int j = 0; j < 4; j++)
                acc[i][j] = mfma16(af[i], bf[j], acc[i][j]);
    }

#pragma unroll
    for (int i = 0; i < 4; i++) {
#pragma unroll
        for (int j = 0; j < 4; j++) {
            const int col = n0 + wc * 64 + j * 16 + fr;
            const float bs = bias[col];
#pragma unroll
            for (int r = 0; r < 4; r++) {
                const int row = m0 + wr * 64 + i * 16 + fg * 4 + r;
                const float v = acc[i][j][r] + bs;
                if (OUTF32)
                    ((float*)outp)[(size_t)row * N + col] = v;
                else
                    ((u16*)outp)[(size_t)row * N + col] = f2bf(v);
            }
        }
    }
}

// ---------------------------------------------------------------------------
// Chunked attention, all 3 levels (blockIdx.z). Block = 256 thr = 4 waves,
// 64 sorted rows per block (16/wave). Flash over 128-key LDS supertiles.
// K staged row-major XOR-swizzled; V staged transposed (d-major) XOR-swizzled.
// ---------------------------------------------------------------------------
__global__ __launch_bounds__(256) void attn_kernel(const u16* __restrict__ qb,
                                                   const u16* __restrict__ kb,
                                                   const u16* __restrict__ vb,
                                                   const int* __restrict__ sidx,
                                                   u16* __restrict__ att0) {
    __shared__ __align__(16) u16 Ksw[128 * 64];
    __shared__ __align__(16) u16 Vt[64 * 128];
    __shared__ __align__(16) u16 Pl[4][16 * 40];

    const int tid = threadIdx.x;
    const int lane = tid & 63;
    const int w = tid >> 6;
    const int fr = lane & 15, fg = lane >> 4;

    const int lvl = blockIdx.z;
    const int C = (lvl == 0) ? 256 : ((lvl == 1) ? 64 : 16);
    const int bh = blockIdx.y;
    const int b = bh >> 4, h = bh & 15;
    const int r0 = blockIdx.x * 64;
    const int* sb = sidx + (lvl * 4 + b) * 4096;
    u16* aout = att0 + (size_t)lvl * 16777216u;

    const int rowbase = r0 + w * 16;
    const int cw = rowbase / C;
    const int kstart = (cw > 0) ? (cw - 1) * C : 0;
    const int kend = (cw + 1) * C;
    const int c0 = r0 / C;
    const int W0 = (c0 > 0) ? (c0 - 1) * C : 0;
    const int cl = (r0 + 63) / C;
    const int W1 = (cl + 1) * C;
    const int nwin = W1 - W0;

    // Q A-fragments (rows rowbase + fr), d halves [0,32) / [32,64)
    const int qorig = sb[rowbase + fr];
    const u16* qp = qb + ((size_t)(b * 4096 + qorig) << 10) + h * 64;
    const u16x8 qf0 = *(const u16x8*)(qp + fg * 8);
    const u16x8 qf1 = *(const u16x8*)(qp + 32 + fg * 8);

    float m[4], l[4];
    f32x4 o[4] = {};
#pragma unroll
    for (int r = 0; r < 4; r++) { m[r] = -1e30f; l[r] = 0.f; }

    for (int st = 0; st < nwin; st += 128) {
        const int nstage = min(128, nwin - st);
        __syncthreads();
        {
            const int jj = tid >> 3;
            const int piece = tid & 7;
#pragma unroll
            for (int j0 = 0; j0 < 128; j0 += 32) {
                const int j = j0 + jj;
                u16x8 kv = {0, 0, 0, 0, 0, 0, 0, 0};
                u16x8 vv = {0, 0, 0, 0, 0, 0, 0, 0};
                if (j < nstage) {
                    const int orig = sb[W0 + st + j];
                    const size_t gofs = ((size_t)(b * 4096 + orig) << 10) + h * 64 + piece * 8;
                    kv = *(const u16x8*)(kb + gofs);
                    vv = *(const u16x8*)(vb + gofs);
                }
                *(u16x8*)&Ksw[j * 64 + ((piece * 8) ^ ((j & 7) << 3))] = kv;
#pragma unroll
                for (int u = 0; u < 8; u++) {
                    const int d = piece * 8 + u;
                    Vt[d * 128 + (j ^ ((d & 7) << 3))] = vv[u];
                }
            }
        }
        __syncthreads();

        const int base = W0 + st;
        const int lo = max(kstart, base) - base;
        const int hi = min(kend, base + nstage) - base;
        for (int kt = lo; kt < hi; kt += 32) {
            const int kr0 = kt + fr;
            const int kr1 = kr0 + 16;
            const u16x8 kf00 = *(const u16x8*)&Ksw[kr0 * 64 + ((fg * 8) ^ ((kr0 & 7) << 3))];
            const u16x8 kf01 = *(const u16x8*)&Ksw[kr0 * 64 + ((32 + fg * 8) ^ ((kr0 & 7) << 3))];
            const u16x8 kf10 = *(const u16x8*)&Ksw[kr1 * 64 + ((fg * 8) ^ ((kr1 & 7) << 3))];
            const u16x8 kf11 = *(const u16x8*)&Ksw[kr1 * 64 + ((32 + fg * 8) ^ ((kr1 & 7) << 3))];
            f32x4 s0 = {0.f, 0.f, 0.f, 0.f}, s1 = {0.f, 0.f, 0.f, 0.f};
            s0 = mfma16(qf0, kf00, s0);
            s0 = mfma16(qf1, kf01, s0);
            s1 = mfma16(qf0, kf10, s1);
            s1 = mfma16(qf1, kf11, s1);
            const bool f1ok = (kt + 16) < hi;
            f32x4 mx;
#pragma unroll
            for (int r = 0; r < 4; r++) {
                s0[r] *= 0.125f;
                s1[r] = f1ok ? s1[r] * 0.125f : -1e30f;
                mx[r] = fmaxf(s0[r], s1[r]);
            }
#pragma unroll
            for (int sh = 1; sh < 16; sh <<= 1)
#pragma unroll
                for (int r = 0; r < 4; r++) mx[r] = fmaxf(mx[r], __shfl_xor(mx[r], sh));
            float alpha[4];
            f32x4 p0, p1, ps;
#pragma unroll
            for (int r = 0; r < 4; r++) {
                const float mn = fmaxf(m[r], mx[r]);
                alpha[r] = exp2f((m[r] - mn) * 1.44269504f);
                m[r] = mn;
                p0[r] = exp2f((s0[r] - mn) * 1.44269504f);
                p1[r] = exp2f((s1[r] - mn) * 1.44269504f);
                ps[r] = p0[r] + p1[r];
            }
#pragma unroll
            for (int sh = 1; sh < 16; sh <<= 1)
#pragma unroll
                for (int r = 0; r < 4; r++) ps[r] += __shfl_xor(ps[r], sh);
            u16* pw = &Pl[w][0];
#pragma unroll
            for (int r = 0; r < 4; r++) {
                l[r] = l[r] * alpha[r] + ps[r];
                const int prow = fg * 4 + r;
                pw[prow * 40 + fr] = f2bf(p0[r]);
                pw[prow * 40 + 16 + fr] = f2bf(p1[r]);
#pragma unroll
                for (int dt = 0; dt < 4; dt++) o[dt][r] *= alpha[r];
            }
            const u16x8 pa = *(const u16x8*)&pw[fr * 40 + fg * 8];
#pragma unroll
            for (int dt = 0; dt < 4; dt++) {
                const int d = dt * 16 + fr;
                const u16x8 vf = *(const u16x8*)&Vt[d * 128 + ((kt + fg * 8) ^ ((d & 7) << 3))];
                o[dt] = mfma16(pa, vf, o[dt]);
            }
        }
    }

#pragma unroll
    for (int r = 0; r < 4; r++) {
        const float inv = 1.0f / l[r];
        const int orow = sb[rowbase + fg * 4 + r];
        u16* op = aout + ((size_t)(b * 4096 + orow) << 10) + h * 64 + fr;
#pragma unroll
        for (int dt = 0; dt < 4; dt++) op[dt * 16] = f2bf(o[dt][r] * inv);
    }
}

// ---------------------------------------------------------------------------
// combine: (a0+a1+a2)/3 -> bf16
// ---------------------------------------------------------------------------
__global__ void combine_kernel(const u16* __restrict__ a0, const u16* __restrict__ a1,
                               const u16* __restrict__ a2, u16* __restrict__ outp, int n) {
    int i = (blockIdx.x * 256 + threadIdx.x) * 8;
    const int stride = gridDim.x * 256 * 8;
    for (; i < n; i += stride) {
        const u16x8 v0 = *(const u16x8*)(a0 + i);
        const u16x8 v1 = *(const u16x8*)(a1 + i);
        const u16x8 v2 = *(const u16x8*)(a2 + i);
        u16x8 ov;
#pragma unroll
        for (int e = 0; e < 8; e++) {
            const float s = (bf2f(v0[e]) + bf2f(v1[e]) + bf2f(v2[e])) * (1.0f / 3.0f);
            ov[e] = f2bf(s);
        }
        *(u16x8*)(outp + i) = ov;
    }
}

// ---------------------------------------------------------------------------
extern "C" void kernel_launch(void* const* d_in, const int* in_sizes, int n_in,
                              void* d_out, int out_size, void* d_ws, size_t ws_size,
                              hipStream_t stream) {
    (void)in_sizes; (void)n_in; (void)out_size; (void)ws_size;
    const float* x  = (const float*)d_in[0];
    const float* Wq = (const float*)d_in[1];
    const float* bq = (const float*)d_in[2];
    const float* Wk = (const float*)d_in[3];
    const float* bk = (const float*)d_in[4];
    const float* Wv = (const float*)d_in[5];
    const float* bv = (const float*)d_in[6];
    const float* Wo = (const float*)d_in[7];
    const float* bo = (const float*)d_in[8];
    const int* wbc = (const int*)d_in[9];
    const int* wbm = (const int*)d_in[10];
    const int* wbf = (const int*)d_in[11];

    const size_t ELT_X = 16777216;  // 16384*1024
    const size_t ELT_W = 1048576;   // 1024*1024

    char* p = (char*)d_ws;
    u16* xb   = (u16*)p; p += ELT_X * 2;   // later reused as 'comb'
    u16* wqb  = (u16*)p; p += ELT_W * 2;
    u16* wkb  = (u16*)p; p += ELT_W * 2;
    u16* wvb  = (u16*)p; p += ELT_W * 2;
    u16* wob  = (u16*)p; p += ELT_W * 2;
    u16* qbuf = (u16*)p; p += ELT_X * 2;
    u16* kbuf = (u16*)p; p += ELT_X * 2;
    u16* vbuf = (u16*)p; p += ELT_X * 2;
    u16* att0 = (u16*)p; p += 3 * ELT_X * 2;
    int* sidx = (int*)p; p += 3 * 4 * 4096 * 4;

    // 1) converts
    cvt_kernel<<<4096, 256, 0, stream>>>(x, xb, (int)ELT_X);
    cvt_kernel<<<512, 256, 0, stream>>>(Wq, wqb, (int)ELT_W);
    cvt_kernel<<<512, 256, 0, stream>>>(Wk, wkb, (int)ELT_W);
    cvt_kernel<<<512, 256, 0, stream>>>(Wv, wvb, (int)ELT_W);
    cvt_kernel<<<512, 256, 0, stream>>>(Wo, wob, (int)ELT_W);

    // 2) stable bucket argsort (3 levels x 4 batches)
    sort_kernel<<<dim3(4, 3), 256, 0, stream>>>(wbc, wbm, wbf, sidx);

    // 3) QKV projections
    gemm_bt<0><<<dim3(128, 8), 256, 0, stream>>>(xb, wqb, bq, qbuf, 16384, 1024, 1024);
    gemm_bt<0><<<dim3(128, 8), 256, 0, stream>>>(xb, wkb, bk, kbuf, 16384, 1024, 1024);
    gemm_bt<0><<<dim3(128, 8), 256, 0, stream>>>(xb, wvb, bv, vbuf, 16384, 1024, 1024);

    // 4) chunked attention, all levels in one launch
    attn_kernel<<<dim3(64, 64, 3), 256, 0, stream>>>(qbuf, kbuf, vbuf, sidx, att0);

    // 5) combine levels -> bf16 (reuse xb)
    combine_kernel<<<4096, 256, 0, stream>>>(att0, att0 + ELT_X, att0 + 2 * ELT_X, xb,
                                             (int)ELT_X);

    // 6) output projection (fp32 out + bias)
    gemm_bt<1><<<dim3(128, 8), 256, 0, stream>>>(xb, wob, bo, d_out, 16384, 1024, 1024);
}